// Round 17
// baseline (110.524 us; speedup 1.0000x reference)
//
#include <hip/hip_runtime.h>
#include <stdint.h>

#define NLVL 16
#define TSIZE 16384
#define HW 512

typedef float vfloat4 __attribute__((ext_vector_type(4)));  // native vec for nt-store

__constant__ int c_n[NLVL] = {16,20,25,32,40,50,64,80,101,128,161,203,256,322,406,512};

__device__ __forceinline__ uint32_t pkmax(uint32_t a, uint32_t b) {
    uint32_t r;
    asm("v_pk_max_u16 %0, %1, %2" : "=v"(r) : "v"(a), "v"(b));
    return r;
}

// One block = one (level, batch, 32x32 output tile). LDS (17952 B):
//   V    [33][68] u32 : vertical window-max (stride 68 -> ~2-way banks)
//   feat [33][34] f2  : gathered features
// Phase A: global->reg + vertical van Herk (scalarized row addressing).
// Phase B: horizontal van Herk + hash + direct gather.
// Phase C: bilinear interp + nt stores.
template<int K>
__device__ __forceinline__ void do_tile(
        const int lvl, const int b, const int tx0, const int ty0,
        const float* __restrict__ x, const float* __restrict__ table,
        float* __restrict__ out, uint32_t* lds) {
    constexpr int gh = 513 - K;
    constexpr float s = (float)gh * (1.0f / 512.0f);   // exact: gh * 2^-9
    const float nf = (float)c_n[lvl];
    const int tid = threadIdx.x;

    const float* xb0 = x + (size_t)b * 2 * HW * HW;
    const float* xb1 = xb0 + HW * HW;
    const float2* tb = (const float2*)table + (size_t)lvl * TSIZE;
    float* ob = out + ((size_t)b * 32 + lvl * 2) * HW * HW;

    if constexpr (K == 1) {
        // gh == 512 -> s == 1.0 -> bilinear is the identity map.
        const int oy = tid >> 3, xo = tx0 + (tid & 7) * 4;
        const int y = ty0 + oy;
        const float4 v0 = *(const float4*)&xb0[y * HW + xo];
        const float4 v1 = *(const float4*)&xb1[y * HW + xo];
        vfloat4 o0, o1;
        {
            const uint32_t i0 = (((uint32_t)(v0.x * nf)) ^ (((uint32_t)(v1.x * nf)) * 2654435761u)) & (TSIZE - 1);
            const uint32_t i1 = (((uint32_t)(v0.y * nf)) ^ (((uint32_t)(v1.y * nf)) * 2654435761u)) & (TSIZE - 1);
            const uint32_t i2 = (((uint32_t)(v0.z * nf)) ^ (((uint32_t)(v1.z * nf)) * 2654435761u)) & (TSIZE - 1);
            const uint32_t i3 = (((uint32_t)(v0.w * nf)) ^ (((uint32_t)(v1.w * nf)) * 2654435761u)) & (TSIZE - 1);
            const float2 f0 = tb[i0], f1 = tb[i1], f2 = tb[i2], f3 = tb[i3];
            o0 = (vfloat4){f0.x, f1.x, f2.x, f3.x};
            o1 = (vfloat4){f0.y, f1.y, f2.y, f3.y};
        }
        const size_t o = (size_t)y * HW + xo;
        __builtin_nontemporal_store(o0, (vfloat4*)&ob[o]);
        __builtin_nontemporal_store(o1, (vfloat4*)&ob[o + (size_t)HW * HW]);
        return;
    }

    uint32_t* V   = lds;                          // [33][68]
    float2*  feat = (float2*)(lds + 33 * 68);     // [33][34]

    const int gy_base = (int)floorf(((float)ty0 + 0.5f) * s - 0.5f);  // may be -1
    const int gx_base = (int)floorf(((float)tx0 + 0.5f) * s - 0.5f);
    const int rmin = max(gy_base, 0);
    const int cmin = max(gx_base, 0);

    // ---- phase A: global->reg load + vertical van Herk, lane = column ----
    {
        const int wv = __builtin_amdgcn_readfirstlane(tid >> 6);  // wave id -> SGPR
        const int c  = tid & 63;
        const int r0 = 8 * wv;
        const int xx = min(cmin + c, HW - 1);
        const int ybase = rmin + r0;
        uint32_t e[K + 8];
#pragma unroll
        for (int t = 0; t < K + 8; ++t) {
            const int yy = min(ybase + t, HW - 1);
            const float v0 = (xb0 + yy * HW)[xx];
            const float v1 = (xb1 + yy * HW)[xx];
            e[t] = (uint32_t)(v0 * nf) | ((uint32_t)(v1 * nf) << 16);
        }
        uint32_t o[9];
        if constexpr (K >= 10) {
            uint32_t sfx[9];
            sfx[8] = e[8];
#pragma unroll
            for (int t = 7; t >= 0; --t) sfx[t] = pkmax(e[t], sfx[t + 1]);
            uint32_t run = e[9];
#pragma unroll
            for (int m = 9; m <= K + 7; ++m) {
                if (m > 9) run = pkmax(run, e[m]);
                if (m >= K - 1) o[m - K + 1] = pkmax(sfx[m - K + 1], run);
            }
        } else {
#pragma unroll
            for (int i = 0; i < 9; ++i) {
                uint32_t m = e[i];
#pragma unroll
                for (int t = 1; t < K; ++t) m = pkmax(m, e[i + t]);
                o[i] = m;
            }
        }
        const int vb = r0 * 68 + c;
#pragma unroll
        for (int t = 0; t < 9; ++t) V[vb + t * 68] = o[t];
    }
    __syncthreads();

    // ---- phase B: horizontal van Herk + hash + direct gather ----
    if (tid < 99) {
        const int i = tid / 3, g = tid % 3;
        constexpr int NE  = 12 + K - 1;
        constexpr int NCH = (NE + 3) >> 2;
        uint32_t f[NCH * 4];
        const uint4* rp = (const uint4*)(V + i * 68 + 12 * g);   // 16B aligned
#pragma unroll
        for (int cc = 0; cc < NCH; ++cc) {
            const uint4 q = rp[cc];
            f[4*cc] = q.x; f[4*cc+1] = q.y; f[4*cc+2] = q.z; f[4*cc+3] = q.w;
        }
        uint32_t wm[12];
        if constexpr (K >= 13) {
            uint32_t sfx[12];
            sfx[11] = f[11];
#pragma unroll
            for (int d = 10; d >= 0; --d) sfx[d] = pkmax(f[d], sfx[d + 1]);
            uint32_t run = f[12];
#pragma unroll
            for (int m = 12; m <= K + 10; ++m) {
                if (m > 12) run = pkmax(run, f[m]);
                if (m >= K - 1) wm[m - K + 1] = pkmax(sfx[m - K + 1], run);
            }
        } else {
#pragma unroll
            for (int d = 0; d < 12; ++d) {
                uint32_t m = f[d];
#pragma unroll
                for (int t = 1; t < K; ++t) m = pkmax(m, f[d + t]);
                wm[d] = m;
            }
        }
#pragma unroll
        for (int d = 0; d < 12; ++d) {
            const int j = 12 * g + d;
            if (j < 33) {
                const uint32_t m = wm[d];
                const uint32_t idx = ((m & 0xFFFFu) ^ ((m >> 16) * 2654435761u)) & (TSIZE - 1);
                feat[i * 34 + j] = tb[idx];
            }
        }
    }
    __syncthreads();

    // ---- phase C: bilinear interp + nontemporal store ----
    const int bty = tid >> 5, btx = tid & 31;
    const int xo = tx0 + btx;
    const float sxf = ((float)xo + 0.5f) * s - 0.5f;
    const float fxf = floorf(sxf);
    const float wx = sxf - fxf;
    const int x0i = (int)fxf;
    const int jx0 = min(max(x0i, 0), gh - 1) - cmin;
    const int jx1 = min(max(x0i + 1, 0), gh - 1) - cmin;
    for (int oy = bty; oy < 32; oy += 8) {
        const int y = ty0 + oy;
        const float syf = ((float)y + 0.5f) * s - 0.5f;
        const float fyf = floorf(syf);
        const float wy = syf - fyf;
        const int y0i = (int)fyf;
        const int iy0 = min(max(y0i, 0), gh - 1) - rmin;
        const int iy1 = min(max(y0i + 1, 0), gh - 1) - rmin;
        const float2 f00 = feat[iy0 * 34 + jx0], f01 = feat[iy0 * 34 + jx1];
        const float2 f10 = feat[iy1 * 34 + jx0], f11 = feat[iy1 * 34 + jx1];
        const float w11 = wy * wx;
        const float w10 = wy - w11;
        const float w01 = wx - w11;
        const float w00 = 1.0f - wy - wx + w11;
        const float c0 = f00.x * w00 + f01.x * w01 + f10.x * w10 + f11.x * w11;
        const float c1 = f00.y * w00 + f01.y * w01 + f10.y * w10 + f11.y * w11;
        const size_t o = (size_t)y * HW + xo;
        __builtin_nontemporal_store(c0, &ob[o]);
        __builtin_nontemporal_store(c1, &ob[o + (size_t)HW * HW]);
    }
}

// Grid order (PHASE-OVERLAP interleave): bid = pair*4096 + tile*16 + half*8 + b
//   lvl = pair + 8*half. Consecutive bids alternate a load-heavy level
//   (pair: K=32..6) with a store/gather-heavy one (pair+8: K<=5) so
//   co-resident blocks are in DIFFERENT phases -> load & store pipes run
//   concurrently instead of bursting in lock-step. b fastest keeps the
//   batch->XCD L2 pinning; only 2 code variants co-resident (I-cache safe).
__global__ __launch_bounds__(256) void fused_kernel(
        const float* __restrict__ x, const float* __restrict__ table,
        float* __restrict__ out) {
    __shared__ __align__(16) uint32_t lds[33 * 68 + 33 * 34 * 2];  // 17952 B

    const int bid  = blockIdx.x;
    const int b    = bid & 7;
    const int half = (bid >> 3) & 1;
    const int tile = (bid >> 4) & 255;
    const int pair = bid >> 12;            // 0..7
    const int lvl  = pair + 8 * half;
    const int tx0  = (tile & 15) * 32;
    const int ty0  = (tile >> 4) * 32;

    switch (lvl) {
        case  0: do_tile<32>( 0, b, tx0, ty0, x, table, out, lds); break;
        case  1: do_tile<25>( 1, b, tx0, ty0, x, table, out, lds); break;
        case  2: do_tile<20>( 2, b, tx0, ty0, x, table, out, lds); break;
        case  3: do_tile<16>( 3, b, tx0, ty0, x, table, out, lds); break;
        case  4: do_tile<12>( 4, b, tx0, ty0, x, table, out, lds); break;
        case  5: do_tile<10>( 5, b, tx0, ty0, x, table, out, lds); break;
        case  6: do_tile< 8>( 6, b, tx0, ty0, x, table, out, lds); break;
        case  7: do_tile< 6>( 7, b, tx0, ty0, x, table, out, lds); break;
        case  8: do_tile< 5>( 8, b, tx0, ty0, x, table, out, lds); break;
        case  9: do_tile< 4>( 9, b, tx0, ty0, x, table, out, lds); break;
        case 10: do_tile< 3>(10, b, tx0, ty0, x, table, out, lds); break;
        case 11: do_tile< 2>(11, b, tx0, ty0, x, table, out, lds); break;
        case 12: do_tile< 2>(12, b, tx0, ty0, x, table, out, lds); break;
        case 13: do_tile< 1>(13, b, tx0, ty0, x, table, out, lds); break;
        case 14: do_tile< 1>(14, b, tx0, ty0, x, table, out, lds); break;
        default: do_tile< 1>(15, b, tx0, ty0, x, table, out, lds); break;
    }
}

extern "C" void kernel_launch(void* const* d_in, const int* in_sizes, int n_in,
                              void* d_out, int out_size, void* d_ws, size_t ws_size,
                              hipStream_t stream) {
    const float* x     = (const float*)d_in[0];
    const float* table = (const float*)d_in[1];
    float* out         = (float*)d_out;
    (void)d_ws; (void)ws_size;

    fused_kernel<<<dim3(NLVL * 256 * 8), dim3(256), 0, stream>>>(x, table, out);
}

// Round 18
// 110.154 us; speedup vs baseline: 1.0034x; 1.0034x over previous
//
#include <hip/hip_runtime.h>
#include <stdint.h>

#define NLVL 16
#define TSIZE 16384
#define HW 512

typedef float vfloat4 __attribute__((ext_vector_type(4)));  // native vec for nt-store

__constant__ int c_n[NLVL] = {16,20,25,32,40,50,64,80,101,128,161,203,256,322,406,512};

__device__ __forceinline__ uint32_t pkmax(uint32_t a, uint32_t b) {
    uint32_t r;
    asm("v_pk_max_u16 %0, %1, %2" : "=v"(r) : "v"(a), "v"(b));
    return r;
}

// One block = one (level, batch, 32x32 output tile). LDS (17952 B):
//   V    [33][68] u32 : vertical window-max (stride 68 -> ~2-way banks)
//   feat [33][34] f2  : gathered features
// Phase A: global->reg + vertical van Herk (scalarized row addressing).
// Phase B: horizontal van Herk + hash + direct gather.
// Phase C: bilinear interp + nt stores.
template<int K>
__device__ __forceinline__ void do_tile(
        const int lvl, const int b, const int tx0, const int ty0,
        const float* __restrict__ x, const float* __restrict__ table,
        float* __restrict__ out, uint32_t* lds) {
    constexpr int gh = 513 - K;
    constexpr float s = (float)gh * (1.0f / 512.0f);   // exact: gh * 2^-9
    const float nf = (float)c_n[lvl];
    const int tid = threadIdx.x;

    const float* xb0 = x + (size_t)b * 2 * HW * HW;
    const float* xb1 = xb0 + HW * HW;
    const float2* tb = (const float2*)table + (size_t)lvl * TSIZE;
    float* ob = out + ((size_t)b * 32 + lvl * 2) * HW * HW;

    if constexpr (K == 1) {
        // gh == 512 -> s == 1.0 -> bilinear is the identity map.
        const int oy = tid >> 3, xo = tx0 + (tid & 7) * 4;
        const int y = ty0 + oy;
        const float4 v0 = *(const float4*)&xb0[y * HW + xo];
        const float4 v1 = *(const float4*)&xb1[y * HW + xo];
        vfloat4 o0, o1;
        {
            const uint32_t i0 = (((uint32_t)(v0.x * nf)) ^ (((uint32_t)(v1.x * nf)) * 2654435761u)) & (TSIZE - 1);
            const uint32_t i1 = (((uint32_t)(v0.y * nf)) ^ (((uint32_t)(v1.y * nf)) * 2654435761u)) & (TSIZE - 1);
            const uint32_t i2 = (((uint32_t)(v0.z * nf)) ^ (((uint32_t)(v1.z * nf)) * 2654435761u)) & (TSIZE - 1);
            const uint32_t i3 = (((uint32_t)(v0.w * nf)) ^ (((uint32_t)(v1.w * nf)) * 2654435761u)) & (TSIZE - 1);
            const float2 f0 = tb[i0], f1 = tb[i1], f2 = tb[i2], f3 = tb[i3];
            o0 = (vfloat4){f0.x, f1.x, f2.x, f3.x};
            o1 = (vfloat4){f0.y, f1.y, f2.y, f3.y};
        }
        const size_t o = (size_t)y * HW + xo;
        __builtin_nontemporal_store(o0, (vfloat4*)&ob[o]);
        __builtin_nontemporal_store(o1, (vfloat4*)&ob[o + (size_t)HW * HW]);
        return;
    }

    uint32_t* V   = lds;                          // [33][68]
    float2*  feat = (float2*)(lds + 33 * 68);     // [33][34]

    const int gy_base = (int)floorf(((float)ty0 + 0.5f) * s - 0.5f);  // may be -1
    const int gx_base = (int)floorf(((float)tx0 + 0.5f) * s - 0.5f);
    const int rmin = max(gy_base, 0);
    const int cmin = max(gx_base, 0);

    // ---- phase A: global->reg load + vertical van Herk, lane = column ----
    {
        const int wv = __builtin_amdgcn_readfirstlane(tid >> 6);  // wave id -> SGPR
        const int c  = tid & 63;
        const int r0 = 8 * wv;
        const int xx = min(cmin + c, HW - 1);
        const int ybase = rmin + r0;
        uint32_t e[K + 8];
#pragma unroll
        for (int t = 0; t < K + 8; ++t) {
            const int yy = min(ybase + t, HW - 1);
            const float v0 = (xb0 + yy * HW)[xx];
            const float v1 = (xb1 + yy * HW)[xx];
            e[t] = (uint32_t)(v0 * nf) | ((uint32_t)(v1 * nf) << 16);
        }
        uint32_t o[9];
        if constexpr (K >= 10) {
            uint32_t sfx[9];
            sfx[8] = e[8];
#pragma unroll
            for (int t = 7; t >= 0; --t) sfx[t] = pkmax(e[t], sfx[t + 1]);
            uint32_t run = e[9];
#pragma unroll
            for (int m = 9; m <= K + 7; ++m) {
                if (m > 9) run = pkmax(run, e[m]);
                if (m >= K - 1) o[m - K + 1] = pkmax(sfx[m - K + 1], run);
            }
        } else {
#pragma unroll
            for (int i = 0; i < 9; ++i) {
                uint32_t m = e[i];
#pragma unroll
                for (int t = 1; t < K; ++t) m = pkmax(m, e[i + t]);
                o[i] = m;
            }
        }
        const int vb = r0 * 68 + c;
#pragma unroll
        for (int t = 0; t < 9; ++t) V[vb + t * 68] = o[t];
    }
    __syncthreads();

    // ---- phase B: horizontal van Herk + hash + direct gather ----
    if (tid < 99) {
        const int i = tid / 3, g = tid % 3;
        constexpr int NE  = 12 + K - 1;
        constexpr int NCH = (NE + 3) >> 2;
        uint32_t f[NCH * 4];
        const uint4* rp = (const uint4*)(V + i * 68 + 12 * g);   // 16B aligned
#pragma unroll
        for (int cc = 0; cc < NCH; ++cc) {
            const uint4 q = rp[cc];
            f[4*cc] = q.x; f[4*cc+1] = q.y; f[4*cc+2] = q.z; f[4*cc+3] = q.w;
        }
        uint32_t wm[12];
        if constexpr (K >= 13) {
            uint32_t sfx[12];
            sfx[11] = f[11];
#pragma unroll
            for (int d = 10; d >= 0; --d) sfx[d] = pkmax(f[d], sfx[d + 1]);
            uint32_t run = f[12];
#pragma unroll
            for (int m = 12; m <= K + 10; ++m) {
                if (m > 12) run = pkmax(run, f[m]);
                if (m >= K - 1) wm[m - K + 1] = pkmax(sfx[m - K + 1], run);
            }
        } else {
#pragma unroll
            for (int d = 0; d < 12; ++d) {
                uint32_t m = f[d];
#pragma unroll
                for (int t = 1; t < K; ++t) m = pkmax(m, f[d + t]);
                wm[d] = m;
            }
        }
#pragma unroll
        for (int d = 0; d < 12; ++d) {
            const int j = 12 * g + d;
            if (j < 33) {
                const uint32_t m = wm[d];
                const uint32_t idx = ((m & 0xFFFFu) ^ ((m >> 16) * 2654435761u)) & (TSIZE - 1);
                feat[i * 34 + j] = tb[idx];
            }
        }
    }
    __syncthreads();

    // ---- phase C: bilinear interp + nontemporal store ----
    const int bty = tid >> 5, btx = tid & 31;
    const int xo = tx0 + btx;
    const float sxf = ((float)xo + 0.5f) * s - 0.5f;
    const float fxf = floorf(sxf);
    const float wx = sxf - fxf;
    const int x0i = (int)fxf;
    const int jx0 = min(max(x0i, 0), gh - 1) - cmin;
    const int jx1 = min(max(x0i + 1, 0), gh - 1) - cmin;
    for (int oy = bty; oy < 32; oy += 8) {
        const int y = ty0 + oy;
        const float syf = ((float)y + 0.5f) * s - 0.5f;
        const float fyf = floorf(syf);
        const float wy = syf - fyf;
        const int y0i = (int)fyf;
        const int iy0 = min(max(y0i, 0), gh - 1) - rmin;
        const int iy1 = min(max(y0i + 1, 0), gh - 1) - rmin;
        const float2 f00 = feat[iy0 * 34 + jx0], f01 = feat[iy0 * 34 + jx1];
        const float2 f10 = feat[iy1 * 34 + jx0], f11 = feat[iy1 * 34 + jx1];
        const float w11 = wy * wx;
        const float w10 = wy - w11;
        const float w01 = wx - w11;
        const float w00 = 1.0f - wy - wx + w11;
        const float c0 = f00.x * w00 + f01.x * w01 + f10.x * w10 + f11.x * w11;
        const float c1 = f00.y * w00 + f01.y * w01 + f10.y * w10 + f11.y * w11;
        const size_t o = (size_t)y * HW + xo;
        __builtin_nontemporal_store(c0, &ob[o]);
        __builtin_nontemporal_store(c1, &ob[o + (size_t)HW * HW]);
    }
}

// Grid order (PHASE-OVERLAP interleave): bid = pair*4096 + tile*16 + half*8 + b
//   lvl = pair + 8*half. Consecutive bids alternate a load-heavy level
//   (pair: K=32..6) with a store/gather-heavy one (pair+8: K<=5) so
//   co-resident blocks are in DIFFERENT phases -> load & store pipes run
//   concurrently instead of bursting in lock-step. b fastest keeps the
//   batch->XCD L2 pinning; only 2 code variants co-resident (I-cache safe).
__global__ __launch_bounds__(256) void fused_kernel(
        const float* __restrict__ x, const float* __restrict__ table,
        float* __restrict__ out) {
    __shared__ __align__(16) uint32_t lds[33 * 68 + 33 * 34 * 2];  // 17952 B

    const int bid  = blockIdx.x;
    const int b    = bid & 7;
    const int half = (bid >> 3) & 1;
    const int tile = (bid >> 4) & 255;
    const int pair = bid >> 12;            // 0..7
    const int lvl  = pair + 8 * half;
    const int tx0  = (tile & 15) * 32;
    const int ty0  = (tile >> 4) * 32;

    switch (lvl) {
        case  0: do_tile<32>( 0, b, tx0, ty0, x, table, out, lds); break;
        case  1: do_tile<25>( 1, b, tx0, ty0, x, table, out, lds); break;
        case  2: do_tile<20>( 2, b, tx0, ty0, x, table, out, lds); break;
        case  3: do_tile<16>( 3, b, tx0, ty0, x, table, out, lds); break;
        case  4: do_tile<12>( 4, b, tx0, ty0, x, table, out, lds); break;
        case  5: do_tile<10>( 5, b, tx0, ty0, x, table, out, lds); break;
        case  6: do_tile< 8>( 6, b, tx0, ty0, x, table, out, lds); break;
        case  7: do_tile< 6>( 7, b, tx0, ty0, x, table, out, lds); break;
        case  8: do_tile< 5>( 8, b, tx0, ty0, x, table, out, lds); break;
        case  9: do_tile< 4>( 9, b, tx0, ty0, x, table, out, lds); break;
        case 10: do_tile< 3>(10, b, tx0, ty0, x, table, out, lds); break;
        case 11: do_tile< 2>(11, b, tx0, ty0, x, table, out, lds); break;
        case 12: do_tile< 2>(12, b, tx0, ty0, x, table, out, lds); break;
        case 13: do_tile< 1>(13, b, tx0, ty0, x, table, out, lds); break;
        case 14: do_tile< 1>(14, b, tx0, ty0, x, table, out, lds); break;
        default: do_tile< 1>(15, b, tx0, ty0, x, table, out, lds); break;
    }
}

extern "C" void kernel_launch(void* const* d_in, const int* in_sizes, int n_in,
                              void* d_out, int out_size, void* d_ws, size_t ws_size,
                              hipStream_t stream) {
    const float* x     = (const float*)d_in[0];
    const float* table = (const float*)d_in[1];
    float* out         = (float*)d_out;
    (void)d_ws; (void)ws_size;

    fused_kernel<<<dim3(NLVL * 256 * 8), dim3(256), 0, stream>>>(x, table, out);
}